// Round 6
// baseline (364.626 us; speedup 1.0000x reference)
//
#include <hip/hip_runtime.h>

#define HH 512
#define WW 512
#define PLANES 96          // 32 * 3
#define RSTRIP 32          // output rows per block; 42 iters (divisible by unroll 6)
#define NPIX 25165824.0f   // 32*3*512*512

// Gaussian weights (sigma=1.5, K=11), symmetric; these exact constants gave absmax 0.0
#define G0 0.2660117f
#define G1 0.2130056f
#define G2 0.1093607f
#define G3 0.0360008f
#define G4 0.0075988f
#define G5 0.0010284f

#define C1F 1e-4f
#define C2F 9e-4f

typedef float v2f __attribute__((ext_vector_type(2)));
#define PKFMA(a, b, c) __builtin_elementwise_fma(a, b, c)

// packed 11-deep histories: AB = (conv(u), conv(v)), PQ = (conv(u^2), conv(v^2))
#define DECL_HIST2(Z) v2f Z##0={0,0},Z##1={0,0},Z##2={0,0},Z##3={0,0},Z##4={0,0},\
                          Z##5={0,0},Z##6={0,0},Z##7={0,0},Z##8={0,0},Z##9={0,0},Z##10={0,0}
#define SHIFT_HIST(Z) do{Z##0=Z##1;Z##1=Z##2;Z##2=Z##3;Z##3=Z##4;Z##4=Z##5;\
                         Z##5=Z##6;Z##6=Z##7;Z##7=Z##8;Z##8=Z##9;Z##9=Z##10;}while(0)
// identical per-component op order as the scalar VCONV that measured absmax 0.0
#define VCONV2(Z) PKFMA(g5, Z##0+Z##10, PKFMA(g4, Z##1+Z##9, PKFMA(g3, Z##2+Z##8,\
                  PKFMA(g2, Z##3+Z##7, PKFMA(g1, Z##4+Z##6, g0*Z##5)))))

// horizontal conv, op order identical to the absmax-0.0 HPAIR sequence
#define HCONV(T0,T1,T2,T3,T4,T5,T6,T7,T8,T9,T10, NAB, NPQ) do { \
    NAB = g0 * (T5);            NPQ = g0 * ((T5) * (T5)); \
    NAB = PKFMA(g1, (T4)+(T6),  NAB); NPQ = PKFMA(g1, PKFMA((T4),(T4),(T6)*(T6)),   NPQ); \
    NAB = PKFMA(g2, (T3)+(T7),  NAB); NPQ = PKFMA(g2, PKFMA((T3),(T3),(T7)*(T7)),   NPQ); \
    NAB = PKFMA(g3, (T2)+(T8),  NAB); NPQ = PKFMA(g3, PKFMA((T2),(T2),(T8)*(T8)),   NPQ); \
    NAB = PKFMA(g4, (T1)+(T9),  NAB); NPQ = PKFMA(g4, PKFMA((T1),(T1),(T9)*(T9)),   NPQ); \
    NAB = PKFMA(g5, (T0)+(T10), NAB); NPQ = PKFMA(g5, PKFMA((T0),(T0),(T10)*(T10)), NPQ); \
} while (0)

#define EPILOG(ZAB, ZPQ) do { \
    const v2f mu = VCONV2(ZAB); \
    const v2f c2 = VCONV2(ZPQ); \
    const float a = mu.x * mu.x; \
    const float b = mu.y * mu.y; \
    const float musq = 0.5f  * (a + b);       /* mu1^2 + mu2^2 */ \
    const float mu12 = 0.25f * (a - b);       /* mu1 * mu2     */ \
    const float csq  = 0.5f  * (c2.x + c2.y); /* conv(x^2)+conv(y^2) */ \
    const float cxy  = 0.25f * (c2.x - c2.y); /* conv(x*y)     */ \
    const float ssum = csq - musq; \
    const float s12  = cxy - mu12; \
    const float num = fmaf(2.f, mu12, C1F) * fmaf(2.f, s12, C2F); \
    const float den = (musq + C1F) * (ssum + C2F); \
    lsum += num * __builtin_amdgcn_rcpf(den); \
} while (0)

// Round 12: R4 falsified the issue-bound theory -- 50M wave-instrs = ~40us at
// full issue, measured 131us @ VALUBusy 84% -> dependent-chain latency with
// only ~2.25 waves/SIMD resident. Occupancy tracks live-register state across
// all rounds (unified VGPR/AGPR file; VGPR_Count under-reports). Fixes:
// (1) register diet: no prefetch set (staging loads double as prefetch),
//     halo via one per-lane delta instead of 2 pointer pairs, builtins not
//     asm, waves_per_eu(4,8) -> target <=128 regs = 4 waves/SIMD.
// (2) cross-iter LDS pipeline: read taps(t) from buf[t&1] (staged last iter),
//     issue row t+1 globals, hconv(t) covers their latency, stage t+1 into
//     buf[(t+1)&1]. Kills the per-iter LDS write->read round-trip; same-wave
//     in-order LDS -> NO barriers. OOB rows staged as zeros -> straight-line
//     body, bit-exact (hconv(0)=0 = old zero path).
__global__ __launch_bounds__(256) __attribute__((amdgpu_waves_per_eu(4, 8)))
void ssim_main(const float* __restrict__ img1,
               const float* __restrict__ img2,
               float* __restrict__ acc) {
    __shared__ __align__(16) v2f luv[2][4][144]; // [parity][wave][slot]; wave-private
    const int tid  = threadIdx.x;
    const int lane = tid & 63;
    const int wv   = tid >> 6;
    const int base = wv * 128;                   // block spans the full 512-col row
    const int r0   = blockIdx.y * RSTRIP;        // first output row of strip
    const int p    = blockIdx.z;                 // plane (b*3+ch)
    const size_t pb = (size_t)p * (HH * WW);
    const int c0   = base + 2 * lane;            // first of this thread's 2 columns

    // halo: lanes 0..4 stage col base-5+lane (slot lane);
    //       lanes 5..11 stage col base+128+(lane-5) (slot 128+lane)
    const bool hl = (lane < 5);
    const bool hhalo = (lane < 12);
    int hcol = hl ? (base - 5 + lane) : (base + 123 + lane);
    const bool hv = hhalo && ((unsigned)hcol < (unsigned)WW);
    if (!hv) hcol = c0;                          // delta 0; loads stay guarded
    const int hdelta = hcol - c0;                // per-lane constant offset
    const int hslot  = hl ? lane : (128 + lane);

    // row pointers at (t, c0); advanced by WW per iteration (deref is guarded)
    const float* rx = img1 + pb + (ptrdiff_t)(r0 - 5) * WW + c0;
    const float* ry = img2 + pb + (ptrdiff_t)(r0 - 5) * WW + c0;

    const v2f g0 = {G0, G0}, g1 = {G1, G1}, g2 = {G2, G2},
              g3 = {G3, G3}, g4 = {G4, G4}, g5 = {G5, G5};

    DECL_HIST2(ABe); DECL_HIST2(PQe);            // even column (c0)
    DECL_HIST2(ABo); DECL_HIST2(PQo);            // odd column (c0+1)

    // prologue: stage row r0-5 (zeros if OOB) into buf[(r0-5)&1]
    {
        const int t0 = r0 - 5;
        v2f xa = {0.f, 0.f}, yb = {0.f, 0.f};
        float hx0 = 0.f, hy0 = 0.f;
        if ((unsigned)t0 < (unsigned)HH) {
            __builtin_memcpy(&xa, rx, 8);
            __builtin_memcpy(&yb, ry, 8);
            if (hv) { hx0 = rx[hdelta]; hy0 = ry[hdelta]; }
        }
        v2f* sb = &luv[t0 & 1][wv][0];
        const v2f u2 = xa + yb, w2 = xa - yb;
        sb[2 * lane + 5] = v2f{u2.x, w2.x};
        sb[2 * lane + 6] = v2f{u2.y, w2.y};
        if (hhalo) sb[hslot] = v2f{hx0 + hy0, hx0 - hy0};
    }

    float lsum = 0.f;
    const int tend = r0 + RSTRIP + 4;

#pragma unroll 6
    for (int t = r0 - 5; t <= tend; ++t, rx += WW, ry += WW) {
        SHIFT_HIST(ABe); SHIFT_HIST(PQe); SHIFT_HIST(ABo); SHIFT_HIST(PQo);

        // 1. taps for row t (staged last iter / prologue; zeros when row OOB)
        const v2f* wp = &luv[t & 1][wv][0] + 2 * lane;  // slots 2l..2l+11, 16B-aligned
        const v2f t0 = wp[0], t1 = wp[1], t2 = wp[2],  t3 = wp[3];
        const v2f t4 = wp[4], t5 = wp[5], t6 = wp[6],  t7 = wp[7];
        const v2f t8 = wp[8], t9 = wp[9], ta = wp[10], tb = wp[11];

        // 2. issue row t+1 global loads (guarded; zeros otherwise)
        v2f xa = {0.f, 0.f}, yb = {0.f, 0.f};
        float hx0 = 0.f, hy0 = 0.f;
        if ((unsigned)(t + 1) < (unsigned)HH) {  // uniform
            __builtin_memcpy(&xa, rx + WW, 8);
            __builtin_memcpy(&yb, ry + WW, 8);
            if (hv) { hx0 = rx[WW + hdelta]; hy0 = ry[WW + hdelta]; }
        }

        // 3. hconv(t) — covers the loads' latency
        v2f nABe = {0,0}, nPQe = {0,0}, nABo = {0,0}, nPQo = {0,0};
        HCONV(t0,t1,t2,t3,t4,t5,t6,t7,t8,t9,ta, nABe, nPQe);   // col c0
        HCONV(t1,t2,t3,t4,t5,t6,t7,t8,t9,ta,tb, nABo, nPQo);   // col c0+1

        // 4. stage row t+1 into the other parity buffer (zeros when OOB)
        {
            v2f* sb = &luv[(t + 1) & 1][wv][0];
            const v2f u2 = xa + yb, w2 = xa - yb;
            sb[2 * lane + 5] = v2f{u2.x, w2.x};
            sb[2 * lane + 6] = v2f{u2.y, w2.y};
            if (hhalo) sb[hslot] = v2f{hx0 + hy0, hx0 - hy0};
        }

        ABe10 = nABe; PQe10 = nPQe; ABo10 = nABo; PQo10 = nPQo;

        const int s = t - 5 - r0;                // output row within strip
        if ((unsigned)s < (unsigned)RSTRIP) {    // uniform; first 10 iters warm up
            EPILOG(ABe, PQe);
            EPILOG(ABo, PQo);
        }
    }

    // reduction: wave shfl -> LDS -> one atomic per block
#pragma unroll
    for (int off = 32; off > 0; off >>= 1)
        lsum += __shfl_down(lsum, off, 64);
    __shared__ float ws4[4];
    if (lane == 0) ws4[wv] = lsum;
    __syncthreads();
    if (threadIdx.x == 0)
        atomicAdd(acc, ws4[0] + ws4[1] + ws4[2] + ws4[3]);
}

__global__ void ssim_zero(float* acc) { acc[0] = 0.f; }

__global__ void ssim_finalize(const float* __restrict__ acc, float* __restrict__ out) {
    out[0] = 1.f - acc[0] * (1.f / NPIX);
}

extern "C" void kernel_launch(void* const* d_in, const int* in_sizes, int n_in,
                              void* d_out, int out_size, void* d_ws, size_t ws_size,
                              hipStream_t stream) {
    const float* img1 = (const float*)d_in[0];
    const float* img2 = (const float*)d_in[1];
    float* out = (float*)d_out;
    float* acc = (float*)d_ws;

    ssim_zero<<<1, 1, 0, stream>>>(acc);
    dim3 grid(1, HH / RSTRIP, PLANES);           // (1, 16, 96) = 1536 blocks
    ssim_main<<<grid, 256, 0, stream>>>(img1, img2, acc);
    ssim_finalize<<<1, 1, 0, stream>>>(acc, out);
}

// Round 7
// 251.517 us; speedup vs baseline: 1.4497x; 1.4497x over previous
//
#include <hip/hip_runtime.h>

#define HH 512
#define WW 512
#define PLANES 96          // 32 * 3
#define RSTRIP 64          // output rows per block; 74 iters, warm-up tax 13.5% (was 24%)
#define NPIX 25165824.0f   // 32*3*512*512

// Gaussian weights (sigma=1.5, K=11), symmetric; these exact constants gave absmax 0.0
#define G0 0.2660117f
#define G1 0.2130056f
#define G2 0.1093607f
#define G3 0.0360008f
#define G4 0.0075988f
#define G5 0.0010284f

#define C1F 1e-4f
#define C2F 9e-4f

typedef float v2f __attribute__((ext_vector_type(2)));
#define PKFMA(a, b, c) __builtin_elementwise_fma(a, b, c)

// packed 11-deep histories: AB = (conv(u), conv(v)), PQ = (conv(u^2), conv(v^2))
#define DECL_HIST2(Z) v2f Z##0={0,0},Z##1={0,0},Z##2={0,0},Z##3={0,0},Z##4={0,0},\
                          Z##5={0,0},Z##6={0,0},Z##7={0,0},Z##8={0,0},Z##9={0,0},Z##10={0,0}
#define SHIFT_HIST(Z) do{Z##0=Z##1;Z##1=Z##2;Z##2=Z##3;Z##3=Z##4;Z##4=Z##5;\
                         Z##5=Z##6;Z##6=Z##7;Z##7=Z##8;Z##8=Z##9;Z##9=Z##10;}while(0)
// identical per-component op order as the scalar VCONV that measured absmax 0.0
#define VCONV2(Z) PKFMA(g5, Z##0+Z##10, PKFMA(g4, Z##1+Z##9, PKFMA(g3, Z##2+Z##8,\
                  PKFMA(g2, Z##3+Z##7, PKFMA(g1, Z##4+Z##6, g0*Z##5)))))

// horizontal conv, op order identical to the absmax-0.0 HPAIR sequence
#define HCONV(T0,T1,T2,T3,T4,T5,T6,T7,T8,T9,T10, NAB, NPQ) do { \
    NAB = g0 * (T5);            NPQ = g0 * ((T5) * (T5)); \
    NAB = PKFMA(g1, (T4)+(T6),  NAB); NPQ = PKFMA(g1, PKFMA((T4),(T4),(T6)*(T6)),   NPQ); \
    NAB = PKFMA(g2, (T3)+(T7),  NAB); NPQ = PKFMA(g2, PKFMA((T3),(T3),(T7)*(T7)),   NPQ); \
    NAB = PKFMA(g3, (T2)+(T8),  NAB); NPQ = PKFMA(g3, PKFMA((T2),(T2),(T8)*(T8)),   NPQ); \
    NAB = PKFMA(g4, (T1)+(T9),  NAB); NPQ = PKFMA(g4, PKFMA((T1),(T1),(T9)*(T9)),   NPQ); \
    NAB = PKFMA(g5, (T0)+(T10), NAB); NPQ = PKFMA(g5, PKFMA((T0),(T0),(T10)*(T10)), NPQ); \
} while (0)

#define EPILOG(ZAB, ZPQ) do { \
    const v2f mu = VCONV2(ZAB); \
    const v2f c2 = VCONV2(ZPQ); \
    const float a = mu.x * mu.x; \
    const float b = mu.y * mu.y; \
    const float musq = 0.5f  * (a + b);       /* mu1^2 + mu2^2 */ \
    const float mu12 = 0.25f * (a - b);       /* mu1 * mu2     */ \
    const float csq  = 0.5f  * (c2.x + c2.y); /* conv(x^2)+conv(y^2) */ \
    const float cxy  = 0.25f * (c2.x - c2.y); /* conv(x*y)     */ \
    const float ssum = csq - musq; \
    const float s12  = cxy - mu12; \
    const float num = fmaf(2.f, mu12, C1F) * fmaf(2.f, s12, C2F); \
    const float den = (musq + C1F) * (ssum + C2F); \
    lsum += num * __builtin_amdgcn_rcpf(den); \
} while (0)

// Round 13: R5's occupancy push spilled (WRITE_SIZE 48KB->22.8MB scratch,
// 230us) -- the 88-float histories + pipeline live state exceed a 128-reg
// budget; unified-file AGPR use explains why occupancy ~ 512/(VGPR+AGPR)
// across all rounds. REVERT to the proven 127us R3 structure; the one safe
// work-reduction knob left: RSTRIP 32->64 cuts the 10-iter warm-up tax from
// 24% to 13.5% of iterations (-12% total work) and halves strip-halo HBM
// re-reads (-31MB). Grid 768 = 3 blocks/CU >= reg-limited residency (~2.25
// blocks/CU) so the smaller grid is not binding. Bit-exact vs R3.
__global__ __launch_bounds__(256) __attribute__((amdgpu_waves_per_eu(3, 8)))
void ssim_main(const float* __restrict__ img1,
               const float* __restrict__ img2,
               float* __restrict__ acc) {
    __shared__ __align__(16) v2f luv[4][144];    // wave-private; slot s <-> col base+s-5
    const int tid  = threadIdx.x;
    const int lane = tid & 63;
    const int wv   = tid >> 6;
    const int base = wv * 128;                   // block spans the full 512-col row
    const int r0   = blockIdx.y * RSTRIP;        // first output row of strip
    const int p    = blockIdx.z;                 // plane (b*3+ch)
    const size_t pb = (size_t)p * (HH * WW);
    const int c0   = base + 2 * lane;            // first of this thread's 2 columns

    // halo: lanes 0..4 stage col base-5+lane (slot lane);
    //       lanes 5..11 stage col base+128+(lane-5) (slot 128+lane)
    const bool hl = (lane < 5);
    const bool hhalo = (lane < 12);
    int hcol = hl ? (base - 5 + lane) : (base + 123 + lane);
    const bool hv = hhalo && ((unsigned)hcol < (unsigned)WW);
    if (!hv) hcol = 0;                           // keep pointer sane; loads are guarded
    const int hslot = hl ? lane : (128 + lane);

    // row pointers at (t, col); advanced by WW per iteration (deref is guarded)
    const float* rx = img1 + pb + (ptrdiff_t)(r0 - 5) * WW + c0;
    const float* ry = img2 + pb + (ptrdiff_t)(r0 - 5) * WW + c0;
    const float* hx = img1 + pb + (ptrdiff_t)(r0 - 5) * WW + hcol;
    const float* hy = img2 + pb + (ptrdiff_t)(r0 - 5) * WW + hcol;

    const v2f g0 = {G0, G0}, g1 = {G1, G1}, g2 = {G2, G2},
              g3 = {G3, G3}, g4 = {G4, G4}, g5 = {G5, G5};

    DECL_HIST2(ABe); DECL_HIST2(PQe);            // even column (c0)
    DECL_HIST2(ABo); DECL_HIST2(PQo);            // odd column (c0+1)

    // prefetch first row (r0-5; guarded, may be <0 on first strip)
    v2f cxv = {0.f, 0.f}, cyv = {0.f, 0.f};
    float chx = 0.f, chy = 0.f;
    if ((unsigned)(r0 - 5) < (unsigned)HH) {
        __builtin_memcpy(&cxv, rx, 8);
        __builtin_memcpy(&cyv, ry, 8);
        if (hv) { chx = hx[0]; chy = hy[0]; }
    }

    v2f* const sb = &luv[wv][0];
    float lsum = 0.f;
    const int tend = r0 + RSTRIP + 4;

#pragma unroll 6
    for (int t = r0 - 5; t <= tend; ++t, rx += WW, ry += WW, hx += WW, hy += WW) {
        SHIFT_HIST(ABe); SHIFT_HIST(PQe); SHIFT_HIST(ABo); SHIFT_HIST(PQo);

        // issue next row's loads first; consumed next iteration (latency hidden)
        v2f nxv = {0.f, 0.f}, nyv = {0.f, 0.f};
        float nhx = 0.f, nhy = 0.f;
        const int tn = t + 1;
        if (tn <= tend && (unsigned)tn < (unsigned)HH) {
            __builtin_memcpy(&nxv, rx + WW, 8);
            __builtin_memcpy(&nyv, ry + WW, 8);
            if (hv) { nhx = hx[WW]; nhy = hy[WW]; }
        }

        v2f nABe = {0,0}, nPQe = {0,0}, nABo = {0,0}, nPQo = {0,0};
        if ((unsigned)t < (unsigned)HH) {        // uniform across block
            // stage (u,v) for own 2 cols (slots 2l+5, 2l+6) + halo (lanes<12)
            const v2f u2 = cxv + cyv;            // (u of col0, u of col1)
            const v2f w2 = cxv - cyv;            // (v of col0, v of col1)
            sb[2 * lane + 5] = v2f{u2.x, w2.x};
            sb[2 * lane + 6] = v2f{u2.y, w2.y};
            if (hhalo) sb[hslot] = v2f{chx + chy, chx - chy};
            __asm__ volatile("" ::: "memory");
            __builtin_amdgcn_wave_barrier();

            // 12-tap window, 16B-aligned -> 6x ds_read_b128
            const v2f* wp = sb + 2 * lane;       // slots 2l..2l+11 = cols c0-5..c0+6
            const v2f t0 = wp[0], t1 = wp[1], t2 = wp[2],  t3 = wp[3];
            const v2f t4 = wp[4], t5 = wp[5], t6 = wp[6],  t7 = wp[7];
            const v2f t8 = wp[8], t9 = wp[9], ta = wp[10], tb = wp[11];
            HCONV(t0,t1,t2,t3,t4,t5,t6,t7,t8,t9,ta, nABe, nPQe);   // col c0
            HCONV(t1,t2,t3,t4,t5,t6,t7,t8,t9,ta,tb, nABo, nPQo);   // col c0+1
            __asm__ volatile("" ::: "memory");
            __builtin_amdgcn_wave_barrier();     // next iter's writes stay below reads
        }
        cxv = nxv; cyv = nyv; chx = nhx; chy = nhy;
        ABe10 = nABe; PQe10 = nPQe; ABo10 = nABo; PQo10 = nPQo;

        const int s = t - 5 - r0;                // output row within strip
        if ((unsigned)s < (unsigned)RSTRIP) {    // uniform; first 10 iters warm up
            EPILOG(ABe, PQe);
            EPILOG(ABo, PQo);
        }
    }

    // reduction: wave shfl -> LDS -> one atomic per block
#pragma unroll
    for (int off = 32; off > 0; off >>= 1)
        lsum += __shfl_down(lsum, off, 64);
    __shared__ float ws4[4];
    if (lane == 0) ws4[wv] = lsum;
    __syncthreads();
    if (threadIdx.x == 0)
        atomicAdd(acc, ws4[0] + ws4[1] + ws4[2] + ws4[3]);
}

__global__ void ssim_zero(float* acc) { acc[0] = 0.f; }

__global__ void ssim_finalize(const float* __restrict__ acc, float* __restrict__ out) {
    out[0] = 1.f - acc[0] * (1.f / NPIX);
}

extern "C" void kernel_launch(void* const* d_in, const int* in_sizes, int n_in,
                              void* d_out, int out_size, void* d_ws, size_t ws_size,
                              hipStream_t stream) {
    const float* img1 = (const float*)d_in[0];
    const float* img2 = (const float*)d_in[1];
    float* out = (float*)d_out;
    float* acc = (float*)d_ws;

    ssim_zero<<<1, 1, 0, stream>>>(acc);
    dim3 grid(1, HH / RSTRIP, PLANES);           // (1, 8, 96) = 768 blocks
    ssim_main<<<grid, 256, 0, stream>>>(img1, img2, acc);
    ssim_finalize<<<1, 1, 0, stream>>>(acc, out);
}